// Round 1
// baseline (383.373 us; speedup 1.0000x reference)
//
#include <hip/hip_runtime.h>
#include <hip/hip_bf16.h>
#include <cstddef>

#define B_  8
#define N_  8192
#define C_  256
#define H_  128
#define W_  128
#define HH  8
#define PP  4
#define DD  32
#define HW  (H_ * W_)

typedef short bf16x8 __attribute__((ext_vector_type(8)));
typedef float f32x4  __attribute__((ext_vector_type(4)));

static __device__ __forceinline__ short f2bf_s(float f) {
    __hip_bfloat16 b = __float2bfloat16(f);
    return *reinterpret_cast<short*>(&b);
}
static __device__ __forceinline__ float bf_s2f(short s) {
    __hip_bfloat16 b = *reinterpret_cast<__hip_bfloat16*>(&s);
    return __bfloat162float(b);
}

// ---------------------------------------------------------------------------
// kT: transpose value (B, C=256, H, W) -> val (B*8, H*W, 32) in bf16
// float4 reads (16 B/lane), bf16x8 writes (16 B/lane), pad-257 LDS (2-way max)
// ---------------------------------------------------------------------------
__global__ __launch_bounds__(256) void kT(const float* __restrict__ value,
                                          __hip_bfloat16* __restrict__ val) {
    __shared__ float tile[32][257];
    const int bh   = blockIdx.y;
    const int pix0 = blockIdx.x * 256;
    const int t    = threadIdx.x;

    const float* src = value + (size_t)bh * 32 * HW + pix0;
#pragma unroll
    for (int i = 0; i < 8; ++i) {
        int d  = i * 4 + (t >> 6);
        int p4 = t & 63;
        float4 v = *(const float4*)&src[(size_t)d * HW + p4 * 4];
        tile[d][p4 * 4 + 0] = v.x;
        tile[d][p4 * 4 + 1] = v.y;
        tile[d][p4 * 4 + 2] = v.z;
        tile[d][p4 * 4 + 3] = v.w;
    }
    __syncthreads();
#pragma unroll
    for (int j = 0; j < 4; ++j) {
        int pix = j * 64 + (t >> 2);
        int d0  = (t & 3) * 8;
        bf16x8 o;
#pragma unroll
        for (int k = 0; k < 8; ++k) o[k] = f2bf_s(tile[d0 + k][pix]);
        *(bf16x8*)&val[((size_t)bh * HW + pix0 + pix) * 32 + d0] = o;
    }
}

// ---------------------------------------------------------------------------
// kP: (merged prep) blocks 0..95: split W_off/W_attn -> Wc_hi/Wc_lo (96x256
// bf16 hi/lo, n-major). blocks 96..111: W_out (256x256 f32 k-major) -> Wt
// (256x256 bf16 n-major).
// ---------------------------------------------------------------------------
__global__ __launch_bounds__(256) void kP(const float* __restrict__ W_off,
                                          const float* __restrict__ W_attn,
                                          short* __restrict__ Wc_hi,
                                          short* __restrict__ Wc_lo,
                                          const float* __restrict__ Wsrc,
                                          __hip_bfloat16* __restrict__ Wt) {
    __shared__ float tile[64][65];
    const int t = threadIdx.x;
    if (blockIdx.x < 96) {
        const int c = blockIdx.x;
        float v = (c < 64) ? W_off[(size_t)t * 64 + c]
                           : W_attn[(size_t)t * 32 + (c - 64)];
        short h = f2bf_s(v);
        short l = f2bf_s(v - bf_s2f(h));
        Wc_hi[(size_t)c * 256 + t] = h;
        Wc_lo[(size_t)c * 256 + t] = l;
    } else {
        const int bx = blockIdx.x - 96;
        const int n0 = (bx & 3) * 64;
        const int k0 = (bx >> 2) * 64;
#pragma unroll
        for (int i = 0; i < 16; ++i) {
            int kk = i * 4 + (t >> 6);
            int nn = t & 63;
            tile[kk][nn] = Wsrc[(size_t)(k0 + kk) * 256 + n0 + nn];
        }
        __syncthreads();
#pragma unroll
        for (int i = 0; i < 16; ++i) {
            int nn = i * 4 + (t >> 6);
            int kk = t & 63;
            Wt[(size_t)(n0 + nn) * 256 + k0 + kk] = __float2bfloat16(tile[kk][nn]);
        }
    }
}

// ---------------------------------------------------------------------------
// kA1M: offset/attn GEMM via bf16 hi/lo MFMA (3-product f32 emulation)
// C = query(128x256) @ Wc^T(96x256)  ->  epilogue softmax + loc
// locattn now n-major: [b][n][h][p] float4 -> 512 B write bursts per rg-group
// ---------------------------------------------------------------------------
__global__ __launch_bounds__(256) void kA1M(const float* __restrict__ query,
                                            const float* __restrict__ refp,
                                            const short* __restrict__ Wc_hi,
                                            const short* __restrict__ Wc_lo,
                                            const float* __restrict__ b_off,
                                            const float* __restrict__ b_attn,
                                            float4* __restrict__ locattn) {
    __shared__ __align__(16) char smem[57344];
    short* As_hi = (short*)smem;              // 128x64 bf16 = 16384 B
    short* As_lo = (short*)(smem + 16384);    // 16384 B
    short* Bs_hi = (short*)(smem + 32768);    // 96x64 bf16 = 12288 B
    short* Bs_lo = (short*)(smem + 45056);    // 12288 B
    float* Ct    = (float*)smem;              // 128x100 f32 = 51200 B (reuse)

    const int t    = threadIdx.x;
    const int lane = t & 63;
    const int w    = t >> 6;
    const int wm   = (w & 1) * 64;
    const int wn   = (w >> 1) * 48;
    const int quad = lane >> 4;
    const int l16  = lane & 15;
    const int row0 = blockIdx.x * 128;

    f32x4 acc[4][3];
#pragma unroll
    for (int mt = 0; mt < 4; ++mt)
#pragma unroll
        for (int nt = 0; nt < 3; ++nt)
            acc[mt][nt] = (f32x4){0.f, 0.f, 0.f, 0.f};

    for (int k0c = 0; k0c < 4; ++k0c) {
        // stage A: query 128x64 f32 -> hi/lo bf16, coalesced float4 loads
#pragma unroll
        for (int i = 0; i < 8; ++i) {
            int f   = t + i * 256;       // 0..2047 float4 index
            int row = f >> 4;
            int kq4 = f & 15;
            float4 q = *(const float4*)&query[(size_t)(row0 + row) * 256 +
                                              k0c * 64 + kq4 * 4];
            short4 hv, lv;
            hv.x = f2bf_s(q.x); lv.x = f2bf_s(q.x - bf_s2f(hv.x));
            hv.y = f2bf_s(q.y); lv.y = f2bf_s(q.y - bf_s2f(hv.y));
            hv.z = f2bf_s(q.z); lv.z = f2bf_s(q.z - bf_s2f(hv.z));
            hv.w = f2bf_s(q.w); lv.w = f2bf_s(q.w - bf_s2f(hv.w));
            int base = row * 64 + (((kq4 >> 1) ^ (row & 7)) * 8) + (kq4 & 1) * 4;
            *(short4*)&As_hi[base] = hv;
            *(short4*)&As_lo[base] = lv;
        }
        // stage B: 96x64 bf16 hi/lo
#pragma unroll
        for (int i = 0; i < 3; ++i) {
            int idx = t + i * 256;       // 0..767 16B-block index
            int n   = idx >> 3;
            int kb  = idx & 7;
            int dst = n * 64 + ((kb ^ (n & 7)) * 8);
            *(uint4*)&Bs_hi[dst] =
                *(const uint4*)&Wc_hi[(size_t)n * 256 + k0c * 64 + kb * 8];
            *(uint4*)&Bs_lo[dst] =
                *(const uint4*)&Wc_lo[(size_t)n * 256 + k0c * 64 + kb * 8];
        }
        __syncthreads();

#pragma unroll
        for (int ks = 0; ks < 2; ++ks) {
            const int kq = ks * 4 + quad;
            bf16x8 ah[4], al[4], bh[3], bl[3];
#pragma unroll
            for (int mt = 0; mt < 4; ++mt) {
                int m = wm + mt * 16 + l16;
                ah[mt] = *(const bf16x8*)&As_hi[m * 64 + (kq ^ (m & 7)) * 8];
                al[mt] = *(const bf16x8*)&As_lo[m * 64 + (kq ^ (m & 7)) * 8];
            }
#pragma unroll
            for (int nt = 0; nt < 3; ++nt) {
                int n = wn + nt * 16 + l16;
                bh[nt] = *(const bf16x8*)&Bs_hi[n * 64 + (kq ^ (n & 7)) * 8];
                bl[nt] = *(const bf16x8*)&Bs_lo[n * 64 + (kq ^ (n & 7)) * 8];
            }
            // three product passes; dependent MFMAs on same acc are 12 apart
#pragma unroll
            for (int mt = 0; mt < 4; ++mt)
#pragma unroll
                for (int nt = 0; nt < 3; ++nt)
                    acc[mt][nt] = __builtin_amdgcn_mfma_f32_16x16x32_bf16(
                        ah[mt], bh[nt], acc[mt][nt], 0, 0, 0);
#pragma unroll
            for (int mt = 0; mt < 4; ++mt)
#pragma unroll
                for (int nt = 0; nt < 3; ++nt)
                    acc[mt][nt] = __builtin_amdgcn_mfma_f32_16x16x32_bf16(
                        ah[mt], bl[nt], acc[mt][nt], 0, 0, 0);
#pragma unroll
            for (int mt = 0; mt < 4; ++mt)
#pragma unroll
                for (int nt = 0; nt < 3; ++nt)
                    acc[mt][nt] = __builtin_amdgcn_mfma_f32_16x16x32_bf16(
                        al[mt], bh[nt], acc[mt][nt], 0, 0, 0);
        }
        __syncthreads();
    }

    // dump acc -> Ct[row][col], stride 100
#pragma unroll
    for (int mt = 0; mt < 4; ++mt) {
#pragma unroll
        for (int nt = 0; nt < 3; ++nt) {
            int col = wn + nt * 16 + l16;
#pragma unroll
            for (int rI = 0; rI < 4; ++rI) {
                int row = wm + mt * 16 + quad * 4 + rI;
                Ct[row * 100 + col] = acc[mt][nt][rI];
            }
        }
    }
    __syncthreads();

    // epilogue: per (row, h) softmax + sampling locations
    const int rg = t >> 3;
    const int h  = t & 7;
    float boff[8];
#pragma unroll
    for (int j = 0; j < 8; ++j) boff[j] = b_off[h * 8 + j];
    float batn[4];
#pragma unroll
    for (int j = 0; j < 4; ++j) batn[j] = b_attn[h * 4 + j];

#pragma unroll
    for (int r = 0; r < 4; ++r) {
        int row  = rg * 4 + r;
        int rowg = row0 + row;           // == b * N_ + n
        float rx = refp[(size_t)rowg * 2 + 0];
        float ry = refp[(size_t)rowg * 2 + 1];
        float4 lg4 = *(const float4*)&Ct[row * 100 + 64 + h * 4];
        float lg[4] = {lg4.x + batn[0], lg4.y + batn[1],
                       lg4.z + batn[2], lg4.w + batn[3]};
        float m = fmaxf(fmaxf(lg[0], lg[1]), fmaxf(lg[2], lg[3]));
        float e[4];
        float s = 0.f;
#pragma unroll
        for (int p = 0; p < 4; ++p) { e[p] = __expf(lg[p] - m); s += e[p]; }
        float inv = 1.f / s;
        float4 o0 = *(const float4*)&Ct[row * 100 + h * 8];
        float4 o1 = *(const float4*)&Ct[row * 100 + h * 8 + 4];
        float ox[4] = {o0.x + boff[0], o0.z + boff[2],
                       o1.x + boff[4], o1.z + boff[6]};
        float oy[4] = {o0.y + boff[1], o0.w + boff[3],
                       o1.y + boff[5], o1.w + boff[7]};
#pragma unroll
        for (int p = 0; p < 4; ++p) {
            float x = (rx * 2.f + ox[p]) * (W_ * 0.5f) - 0.5f;
            float y = (ry * 2.f + oy[p]) * (H_ * 0.5f) - 0.5f;
            // n-major layout: [rowg][h][p], 512 B bursts per 8-h group
            locattn[(size_t)rowg * 32 + h * 4 + p] =
                make_float4(x, y, e[p] * inv, 0.f);
        }
    }
}

// ---------------------------------------------------------------------------
// kA2: bilinear sampling + attention weighting -> mid (B*N, 256) bf16
// locattn read adapted to n-major layout (64 B chunks per (n, h))
// ---------------------------------------------------------------------------
__global__ __launch_bounds__(256) void kA2(const float4* __restrict__ locattn,
                                           const __hip_bfloat16* __restrict__ val,
                                           __hip_bfloat16* __restrict__ mid) {
    __shared__ float2 ow[64][4][4];

    const int t  = threadIdx.x;
    const int bh = blockIdx.y;
    const int b  = bh >> 3;
    const int h  = bh & 7;
    const int n0 = blockIdx.x * 64;

    {
        const int r = t >> 2;
        const int p = t & 3;
        float4 L = locattn[((size_t)b * N_ + n0 + r) * 32 + h * 4 + p];
        float x = L.x, y = L.y, a = L.z;
        float xf = floorf(x), yf = floorf(y);
        int x0 = (int)xf, y0 = (int)yf;
        int x1 = x0 + 1, y1 = y0 + 1;
        float wx1 = x - xf, wy1 = y - yf;
        float wx0 = 1.f - wx1, wy0 = 1.f - wy1;
        int cx0 = min(max(x0, 0), W_ - 1);
        int cx1 = min(max(x1, 0), W_ - 1);
        int cy0 = min(max(y0, 0), H_ - 1);
        int cy1 = min(max(y1, 0), H_ - 1);
        bool bx0 = (x0 >= 0) & (x0 < W_);
        bool bx1 = (x1 >= 0) & (x1 < W_);
        bool by0 = (y0 >= 0) & (y0 < H_);
        bool by1 = (y1 >= 0) & (y1 < H_);
        float w00 = a * wx0 * wy0 * ((bx0 & by0) ? 1.f : 0.f);
        float w10 = a * wx1 * wy0 * ((bx1 & by0) ? 1.f : 0.f);
        float w01 = a * wx0 * wy1 * ((bx0 & by1) ? 1.f : 0.f);
        float w11 = a * wx1 * wy1 * ((bx1 & by1) ? 1.f : 0.f);
        ow[r][p][0] = make_float2(__int_as_float(cy0 * W_ + cx0), w00);
        ow[r][p][1] = make_float2(__int_as_float(cy0 * W_ + cx1), w10);
        ow[r][p][2] = make_float2(__int_as_float(cy1 * W_ + cx0), w01);
        ow[r][p][3] = make_float2(__int_as_float(cy1 * W_ + cx1), w11);
    }
    __syncthreads();

    const int d  = t & 31;
    const int rg = t >> 5;
    const __hip_bfloat16* vb = val + (size_t)bh * HW * DD + d;
    __hip_bfloat16* mo = mid + ((size_t)b * N_ + n0) * C_ + h * DD + d;

#pragma unroll
    for (int j = 0; j < 8; ++j) {
        int r = rg * 8 + j;
        const float4* owp = (const float4*)&ow[r][0][0];
        float acc = 0.f;
#pragma unroll
        for (int p = 0; p < 4; ++p) {
            float4 u0 = owp[p * 2 + 0];
            float4 u1 = owp[p * 2 + 1];
            int o00 = __float_as_int(u0.x) * DD;
            int o10 = __float_as_int(u0.z) * DD;
            int o01 = __float_as_int(u1.x) * DD;
            int o11 = __float_as_int(u1.z) * DD;
            acc += u0.y * __bfloat162float(vb[o00]);
            acc += u0.w * __bfloat162float(vb[o10]);
            acc += u1.y * __bfloat162float(vb[o01]);
            acc += u1.w * __bfloat162float(vb[o11]);
        }
        mo[r * C_] = __float2bfloat16(acc);
    }
}

// ---------------------------------------------------------------------------
// kC: out = mid (65536x256 bf16) @ Wt^T (n-major bf16) + bias, MFMA
// ---------------------------------------------------------------------------
__global__ __launch_bounds__(256) void kC(const short* __restrict__ mid,
                                          const short* __restrict__ Wt,
                                          const float* __restrict__ bias,
                                          float* __restrict__ out) {
    __shared__ __align__(16) short As[128 * 64];
    __shared__ __align__(16) short Bs[128 * 64];

    const int t    = threadIdx.x;
    const int lane = t & 63;
    const int w    = t >> 6;
    const int wm   = (w & 1) * 64;
    const int wn   = (w >> 1) * 64;
    const int row0 = blockIdx.x * 128;
    const int col0 = blockIdx.y * 128;

    f32x4 acc[4][4];
#pragma unroll
    for (int mt = 0; mt < 4; ++mt)
#pragma unroll
        for (int nt = 0; nt < 4; ++nt)
            acc[mt][nt] = (f32x4){0.f, 0.f, 0.f, 0.f};

    const int sr = t >> 3;
    const int kb = t & 7;

    for (int k0 = 0; k0 < 4; ++k0) {
#pragma unroll
        for (int i = 0; i < 4; ++i) {
            int row  = sr + i * 32;
            int kbs  = (kb ^ (row & 7)) * 8;
            *(uint4*)&As[row * 64 + kbs] =
                *(const uint4*)&mid[(size_t)(row0 + row) * 256 + k0 * 64 + kb * 8];
            *(uint4*)&Bs[row * 64 + kbs] =
                *(const uint4*)&Wt[(size_t)(col0 + row) * 256 + k0 * 64 + kb * 8];
        }
        __syncthreads();

#pragma unroll
        for (int ks = 0; ks < 2; ++ks) {
            const int kq = ks * 4 + (lane >> 4);
            bf16x8 af[4], bf[4];
#pragma unroll
            for (int mt = 0; mt < 4; ++mt) {
                int m = wm + mt * 16 + (lane & 15);
                af[mt] = *(const bf16x8*)&As[m * 64 + (kq ^ (m & 7)) * 8];
            }
#pragma unroll
            for (int nt = 0; nt < 4; ++nt) {
                int n = wn + nt * 16 + (lane & 15);
                bf[nt] = *(const bf16x8*)&Bs[n * 64 + (kq ^ (n & 7)) * 8];
            }
#pragma unroll
            for (int mt = 0; mt < 4; ++mt)
#pragma unroll
                for (int nt = 0; nt < 4; ++nt)
                    acc[mt][nt] = __builtin_amdgcn_mfma_f32_16x16x32_bf16(
                        af[mt], bf[nt], acc[mt][nt], 0, 0, 0);
        }
        __syncthreads();
    }

    const int cq = lane >> 4;
#pragma unroll
    for (int nt = 0; nt < 4; ++nt) {
        int col  = col0 + wn + nt * 16 + (lane & 15);
        float bv = bias[col];
#pragma unroll
        for (int mt = 0; mt < 4; ++mt) {
#pragma unroll
            for (int rI = 0; rI < 4; ++rI) {
                int rowg = row0 + wm + mt * 16 + cq * 4 + rI;
                out[(size_t)rowg * 256 + col] = acc[mt][nt][rI] + bv;
            }
        }
    }
}

// ---------------------------------------------------------------------------
// launcher
// ws: val     [0,          67108864)  B*8*HW*32 bf16
//     locattn [67108864,  100663296)  B*N*32 float4  (n-major)
//     mid     [100663296, 134217728)  B*N*256 bf16
//     Wt      [134217728, 134348800)  256*256 bf16
//     Wc_hi   [134348800, 134397952)  96*256 bf16
//     Wc_lo   [134397952, 134447104)  96*256 bf16
// ---------------------------------------------------------------------------
extern "C" void kernel_launch(void* const* d_in, const int* in_sizes, int n_in,
                              void* d_out, int out_size, void* d_ws, size_t ws_size,
                              hipStream_t stream) {
    const float* query  = (const float*)d_in[0];
    const float* refp   = (const float*)d_in[1];
    const float* value  = (const float*)d_in[2];
    const float* W_off  = (const float*)d_in[3];
    const float* b_off  = (const float*)d_in[4];
    const float* W_attn = (const float*)d_in[5];
    const float* b_attn = (const float*)d_in[6];
    const float* W_out  = (const float*)d_in[7];
    const float* b_out  = (const float*)d_in[8];
    float* out = (float*)d_out;

    char*           ws      = (char*)d_ws;
    __hip_bfloat16* val     = (__hip_bfloat16*)(ws);
    float4*         locattn = (float4*)(ws + 67108864);
    __hip_bfloat16* mid     = (__hip_bfloat16*)(ws + 100663296);
    __hip_bfloat16* Wt      = (__hip_bfloat16*)(ws + 134217728);
    short*          Wc_hi   = (short*)(ws + 134348800);
    short*          Wc_lo   = (short*)(ws + 134397952);

    kT  <<<dim3(HW / 256, B_ * HH), 256, 0, stream>>>(value, val);
    kP  <<<dim3(112), 256, 0, stream>>>(W_off, W_attn, Wc_hi, Wc_lo, W_out, Wt);
    kA1M<<<dim3((B_ * N_) / 128), 256, 0, stream>>>(query, refp, Wc_hi, Wc_lo,
                                                    b_off, b_attn, locattn);
    kA2 <<<dim3(N_ / 64, B_ * HH), 256, 0, stream>>>(locattn, val, mid);
    kC  <<<dim3((B_ * N_) / 128, C_ / 128), 256, 0, stream>>>(
        (const short*)mid, (const short*)Wt, b_out, out);
}

// Round 3
// 381.609 us; speedup vs baseline: 1.0046x; 1.0046x over previous
//
#include <hip/hip_runtime.h>
#include <hip/hip_bf16.h>
#include <cstddef>

#define B_  8
#define N_  8192
#define C_  256
#define H_  128
#define W_  128
#define HH  8
#define PP  4
#define DD  32
#define HW  (H_ * W_)

typedef short bf16x8 __attribute__((ext_vector_type(8)));
typedef float f32x4  __attribute__((ext_vector_type(4)));

static __device__ __forceinline__ short f2bf_s(float f) {
    __hip_bfloat16 b = __float2bfloat16(f);
    return *reinterpret_cast<short*>(&b);
}
static __device__ __forceinline__ float bf_s2f(short s) {
    __hip_bfloat16 b = *reinterpret_cast<__hip_bfloat16*>(&s);
    return __bfloat162float(b);
}

// ---------------------------------------------------------------------------
// kTP: merged prep kernel.
//  blocks [0, 4096):    transpose value (B,256,H,W) f32 -> val (B*8, HW, 32) bf16
//  blocks [4096, 4192): split W_off/W_attn -> Wc_hi/Wc_lo (96x256 hi/lo bf16)
//  blocks [4192, 4208): W_out (256x256 f32 k-major) -> Wt (256x256 bf16 n-major)
// ---------------------------------------------------------------------------
__global__ __launch_bounds__(256) void kTP(const float* __restrict__ value,
                                           __hip_bfloat16* __restrict__ val,
                                           const float* __restrict__ W_off,
                                           const float* __restrict__ W_attn,
                                           short* __restrict__ Wc_hi,
                                           short* __restrict__ Wc_lo,
                                           const float* __restrict__ Wsrc,
                                           __hip_bfloat16* __restrict__ Wt) {
    __shared__ __align__(16) char smem[33024];
    const int t   = threadIdx.x;
    const int bid = blockIdx.x;

    if (bid < 4096) {
        // ---- transpose part ----
        float (*tile)[257] = (float (*)[257])smem;   // 32x257 f32 = 32896 B
        const int bh   = bid >> 6;
        const int pix0 = (bid & 63) * 256;
        const float* src = value + (size_t)bh * 32 * HW + pix0;
#pragma unroll
        for (int i = 0; i < 8; ++i) {
            int d  = i * 4 + (t >> 6);
            int p4 = t & 63;
            float4 v = *(const float4*)&src[(size_t)d * HW + p4 * 4];
            tile[d][p4 * 4 + 0] = v.x;
            tile[d][p4 * 4 + 1] = v.y;
            tile[d][p4 * 4 + 2] = v.z;
            tile[d][p4 * 4 + 3] = v.w;
        }
        __syncthreads();
#pragma unroll
        for (int j = 0; j < 4; ++j) {
            int pix = j * 64 + (t >> 2);
            int d0  = (t & 3) * 8;
            bf16x8 o;
#pragma unroll
            for (int k = 0; k < 8; ++k) o[k] = f2bf_s(tile[d0 + k][pix]);
            *(bf16x8*)&val[((size_t)bh * HW + pix0 + pix) * 32 + d0] = o;
        }
    } else if (bid < 4192) {
        // ---- Wc hi/lo split ----
        const int c = bid - 4096;
        float v = (c < 64) ? W_off[(size_t)t * 64 + c]
                           : W_attn[(size_t)t * 32 + (c - 64)];
        short h = f2bf_s(v);
        short l = f2bf_s(v - bf_s2f(h));
        Wc_hi[(size_t)c * 256 + t] = h;
        Wc_lo[(size_t)c * 256 + t] = l;
    } else {
        // ---- W_out transpose ----
        float (*tile)[65] = (float (*)[65])smem;     // 64x65 f32 = 16640 B
        const int bx = bid - 4192;
        const int n0 = (bx & 3) * 64;
        const int k0 = (bx >> 2) * 64;
#pragma unroll
        for (int i = 0; i < 16; ++i) {
            int kk = i * 4 + (t >> 6);
            int nn = t & 63;
            tile[kk][nn] = Wsrc[(size_t)(k0 + kk) * 256 + n0 + nn];
        }
        __syncthreads();
#pragma unroll
        for (int i = 0; i < 16; ++i) {
            int nn = i * 4 + (t >> 6);
            int kk = t & 63;
            Wt[(size_t)(n0 + nn) * 256 + k0 + kk] = __float2bfloat16(tile[kk][nn]);
        }
    }
}

// ---------------------------------------------------------------------------
// kA1M: offset/attn GEMM via bf16 hi/lo MFMA (3-product f32 emulation)
// C = query(128x256) @ Wc^T(96x256)  ->  epilogue softmax + loc
// ---------------------------------------------------------------------------
__global__ __launch_bounds__(256) void kA1M(const float* __restrict__ query,
                                            const float* __restrict__ refp,
                                            const short* __restrict__ Wc_hi,
                                            const short* __restrict__ Wc_lo,
                                            const float* __restrict__ b_off,
                                            const float* __restrict__ b_attn,
                                            float4* __restrict__ locattn) {
    __shared__ __align__(16) char smem[57344];
    short* As_hi = (short*)smem;              // 128x64 bf16 = 16384 B
    short* As_lo = (short*)(smem + 16384);    // 16384 B
    short* Bs_hi = (short*)(smem + 32768);    // 96x64 bf16 = 12288 B
    short* Bs_lo = (short*)(smem + 45056);    // 12288 B
    float* Ct    = (float*)smem;              // 128x100 f32 = 51200 B (reuse)

    const int t    = threadIdx.x;
    const int lane = t & 63;
    const int w    = t >> 6;
    const int wm   = (w & 1) * 64;
    const int wn   = (w >> 1) * 48;
    const int quad = lane >> 4;
    const int l16  = lane & 15;
    const int row0 = blockIdx.x * 128;

    f32x4 acc[4][3];
#pragma unroll
    for (int mt = 0; mt < 4; ++mt)
#pragma unroll
        for (int nt = 0; nt < 3; ++nt)
            acc[mt][nt] = (f32x4){0.f, 0.f, 0.f, 0.f};

    for (int k0c = 0; k0c < 4; ++k0c) {
        // stage A: query 128x64 f32 -> hi/lo bf16, coalesced float4 loads
#pragma unroll
        for (int i = 0; i < 8; ++i) {
            int f   = t + i * 256;       // 0..2047 float4 index
            int row = f >> 4;
            int kq4 = f & 15;
            float4 q = *(const float4*)&query[(size_t)(row0 + row) * 256 +
                                              k0c * 64 + kq4 * 4];
            short4 hv, lv;
            hv.x = f2bf_s(q.x); lv.x = f2bf_s(q.x - bf_s2f(hv.x));
            hv.y = f2bf_s(q.y); lv.y = f2bf_s(q.y - bf_s2f(hv.y));
            hv.z = f2bf_s(q.z); lv.z = f2bf_s(q.z - bf_s2f(hv.z));
            hv.w = f2bf_s(q.w); lv.w = f2bf_s(q.w - bf_s2f(hv.w));
            int base = row * 64 + (((kq4 >> 1) ^ (row & 7)) * 8) + (kq4 & 1) * 4;
            *(short4*)&As_hi[base] = hv;
            *(short4*)&As_lo[base] = lv;
        }
        // stage B: 96x64 bf16 hi/lo
#pragma unroll
        for (int i = 0; i < 3; ++i) {
            int idx = t + i * 256;       // 0..767 16B-block index
            int n   = idx >> 3;
            int kb  = idx & 7;
            int dst = n * 64 + ((kb ^ (n & 7)) * 8);
            *(uint4*)&Bs_hi[dst] =
                *(const uint4*)&Wc_hi[(size_t)n * 256 + k0c * 64 + kb * 8];
            *(uint4*)&Bs_lo[dst] =
                *(const uint4*)&Wc_lo[(size_t)n * 256 + k0c * 64 + kb * 8];
        }
        __syncthreads();

#pragma unroll
        for (int ks = 0; ks < 2; ++ks) {
            const int kq = ks * 4 + quad;
            bf16x8 ah[4], al[4], bh[3], bl[3];
#pragma unroll
            for (int mt = 0; mt < 4; ++mt) {
                int m = wm + mt * 16 + l16;
                ah[mt] = *(const bf16x8*)&As_hi[m * 64 + (kq ^ (m & 7)) * 8];
                al[mt] = *(const bf16x8*)&As_lo[m * 64 + (kq ^ (m & 7)) * 8];
            }
#pragma unroll
            for (int nt = 0; nt < 3; ++nt) {
                int n = wn + nt * 16 + l16;
                bh[nt] = *(const bf16x8*)&Bs_hi[n * 64 + (kq ^ (n & 7)) * 8];
                bl[nt] = *(const bf16x8*)&Bs_lo[n * 64 + (kq ^ (n & 7)) * 8];
            }
            // three product passes; dependent MFMAs on same acc are 12 apart
#pragma unroll
            for (int mt = 0; mt < 4; ++mt)
#pragma unroll
                for (int nt = 0; nt < 3; ++nt)
                    acc[mt][nt] = __builtin_amdgcn_mfma_f32_16x16x32_bf16(
                        ah[mt], bh[nt], acc[mt][nt], 0, 0, 0);
#pragma unroll
            for (int mt = 0; mt < 4; ++mt)
#pragma unroll
                for (int nt = 0; nt < 3; ++nt)
                    acc[mt][nt] = __builtin_amdgcn_mfma_f32_16x16x32_bf16(
                        ah[mt], bl[nt], acc[mt][nt], 0, 0, 0);
#pragma unroll
            for (int mt = 0; mt < 4; ++mt)
#pragma unroll
                for (int nt = 0; nt < 3; ++nt)
                    acc[mt][nt] = __builtin_amdgcn_mfma_f32_16x16x32_bf16(
                        al[mt], bh[nt], acc[mt][nt], 0, 0, 0);
        }
        __syncthreads();
    }

    // dump acc -> Ct[row][col], stride 100
#pragma unroll
    for (int mt = 0; mt < 4; ++mt) {
#pragma unroll
        for (int nt = 0; nt < 3; ++nt) {
            int col = wn + nt * 16 + l16;
#pragma unroll
            for (int rI = 0; rI < 4; ++rI) {
                int row = wm + mt * 16 + quad * 4 + rI;
                Ct[row * 100 + col] = acc[mt][nt][rI];
            }
        }
    }
    __syncthreads();

    // epilogue: per (row, h) softmax + sampling locations
    const int rg = t >> 3;
    const int h  = t & 7;
    float boff[8];
#pragma unroll
    for (int j = 0; j < 8; ++j) boff[j] = b_off[h * 8 + j];
    float batn[4];
#pragma unroll
    for (int j = 0; j < 4; ++j) batn[j] = b_attn[h * 4 + j];

#pragma unroll
    for (int r = 0; r < 4; ++r) {
        int row  = rg * 4 + r;
        int rowg = row0 + row;           // == b * N_ + n
        float rx = refp[(size_t)rowg * 2 + 0];
        float ry = refp[(size_t)rowg * 2 + 1];
        float4 lg4 = *(const float4*)&Ct[row * 100 + 64 + h * 4];
        float lg[4] = {lg4.x + batn[0], lg4.y + batn[1],
                       lg4.z + batn[2], lg4.w + batn[3]};
        float m = fmaxf(fmaxf(lg[0], lg[1]), fmaxf(lg[2], lg[3]));
        float e[4];
        float s = 0.f;
#pragma unroll
        for (int p = 0; p < 4; ++p) { e[p] = __expf(lg[p] - m); s += e[p]; }
        float inv = 1.f / s;
        float4 o0 = *(const float4*)&Ct[row * 100 + h * 8];
        float4 o1 = *(const float4*)&Ct[row * 100 + h * 8 + 4];
        float ox[4] = {o0.x + boff[0], o0.z + boff[2],
                       o1.x + boff[4], o1.z + boff[6]};
        float oy[4] = {o0.y + boff[1], o0.w + boff[3],
                       o1.y + boff[5], o1.w + boff[7]};
#pragma unroll
        for (int p = 0; p < 4; ++p) {
            float x = (rx * 2.f + ox[p]) * (W_ * 0.5f) - 0.5f;
            float y = (ry * 2.f + oy[p]) * (H_ * 0.5f) - 0.5f;
            locattn[(size_t)rowg * 32 + h * 4 + p] =
                make_float4(x, y, e[p] * inv, 0.f);
        }
    }
}

// ---------------------------------------------------------------------------
// kA2: bilinear sampling + attention weighting -> mid (B*N, 256) bf16
// XCD-aware block remap: with round-robin dispatch (xcd = bid & 7), each XCD
// sweeps all 128 n-chunks of one bh slice before moving to the next, so the
// resident working set per XCD is ~2 slices (2 MB) << 4 MB L2 -> val gathers
// become L2 hits instead of streaming 537 MB from L3.
// ---------------------------------------------------------------------------
__global__ __launch_bounds__(256) void kA2(const float4* __restrict__ locattn,
                                           const __hip_bfloat16* __restrict__ val,
                                           __hip_bfloat16* __restrict__ mid) {
    __shared__ float2 ow[64][4][4];

    const int t   = threadIdx.x;
    const int bid = blockIdx.x;
    const int xcd = bid & 7;
    const int j_  = bid >> 3;               // 0..1023
    const int bh  = xcd * 8 + (j_ >> 7);    // 8 slices per XCD, swept serially
    const int n0  = (j_ & 127) * 64;
    const int b   = bh >> 3;
    const int h   = bh & 7;

    {
        const int r = t >> 2;
        const int p = t & 3;
        float4 L = locattn[((size_t)b * N_ + n0 + r) * 32 + h * 4 + p];
        float x = L.x, y = L.y, a = L.z;
        float xf = floorf(x), yf = floorf(y);
        int x0 = (int)xf, y0 = (int)yf;
        int x1 = x0 + 1, y1 = y0 + 1;
        float wx1 = x - xf, wy1 = y - yf;
        float wx0 = 1.f - wx1, wy0 = 1.f - wy1;
        int cx0 = min(max(x0, 0), W_ - 1);
        int cx1 = min(max(x1, 0), W_ - 1);
        int cy0 = min(max(y0, 0), H_ - 1);
        int cy1 = min(max(y1, 0), H_ - 1);
        bool bx0 = (x0 >= 0) & (x0 < W_);
        bool bx1 = (x1 >= 0) & (x1 < W_);
        bool by0 = (y0 >= 0) & (y0 < H_);
        bool by1 = (y1 >= 0) & (y1 < H_);
        float w00 = a * wx0 * wy0 * ((bx0 & by0) ? 1.f : 0.f);
        float w10 = a * wx1 * wy0 * ((bx1 & by0) ? 1.f : 0.f);
        float w01 = a * wx0 * wy1 * ((bx0 & by1) ? 1.f : 0.f);
        float w11 = a * wx1 * wy1 * ((bx1 & by1) ? 1.f : 0.f);
        ow[r][p][0] = make_float2(__int_as_float(cy0 * W_ + cx0), w00);
        ow[r][p][1] = make_float2(__int_as_float(cy0 * W_ + cx1), w10);
        ow[r][p][2] = make_float2(__int_as_float(cy1 * W_ + cx0), w01);
        ow[r][p][3] = make_float2(__int_as_float(cy1 * W_ + cx1), w11);
    }
    __syncthreads();

    const int d  = t & 31;
    const int rg = t >> 5;
    const __hip_bfloat16* vb = val + (size_t)bh * HW * DD + d;
    __hip_bfloat16* mo = mid + ((size_t)b * N_ + n0) * C_ + h * DD + d;

#pragma unroll
    for (int j = 0; j < 8; ++j) {
        int r = rg * 8 + j;
        const float4* owp = (const float4*)&ow[r][0][0];
        float acc = 0.f;
#pragma unroll
        for (int p = 0; p < 4; ++p) {
            float4 u0 = owp[p * 2 + 0];
            float4 u1 = owp[p * 2 + 1];
            int o00 = __float_as_int(u0.x) * DD;
            int o10 = __float_as_int(u0.z) * DD;
            int o01 = __float_as_int(u1.x) * DD;
            int o11 = __float_as_int(u1.z) * DD;
            acc += u0.y * __bfloat162float(vb[o00]);
            acc += u0.w * __bfloat162float(vb[o10]);
            acc += u1.y * __bfloat162float(vb[o01]);
            acc += u1.w * __bfloat162float(vb[o11]);
        }
        mo[r * C_] = __float2bfloat16(acc);
    }
}

// ---------------------------------------------------------------------------
// kC: out = mid (65536x256 bf16) @ Wt^T (n-major bf16) + bias, MFMA
// ---------------------------------------------------------------------------
__global__ __launch_bounds__(256) void kC(const short* __restrict__ mid,
                                          const short* __restrict__ Wt,
                                          const float* __restrict__ bias,
                                          float* __restrict__ out) {
    __shared__ __align__(16) short As[128 * 64];
    __shared__ __align__(16) short Bs[128 * 64];

    const int t    = threadIdx.x;
    const int lane = t & 63;
    const int w    = t >> 6;
    const int wm   = (w & 1) * 64;
    const int wn   = (w >> 1) * 64;
    const int row0 = blockIdx.x * 128;
    const int col0 = blockIdx.y * 128;

    f32x4 acc[4][4];
#pragma unroll
    for (int mt = 0; mt < 4; ++mt)
#pragma unroll
        for (int nt = 0; nt < 4; ++nt)
            acc[mt][nt] = (f32x4){0.f, 0.f, 0.f, 0.f};

    const int sr = t >> 3;
    const int kb = t & 7;

    for (int k0 = 0; k0 < 4; ++k0) {
#pragma unroll
        for (int i = 0; i < 4; ++i) {
            int row  = sr + i * 32;
            int kbs  = (kb ^ (row & 7)) * 8;
            *(uint4*)&As[row * 64 + kbs] =
                *(const uint4*)&mid[(size_t)(row0 + row) * 256 + k0 * 64 + kb * 8];
            *(uint4*)&Bs[row * 64 + kbs] =
                *(const uint4*)&Wt[(size_t)(col0 + row) * 256 + k0 * 64 + kb * 8];
        }
        __syncthreads();

#pragma unroll
        for (int ks = 0; ks < 2; ++ks) {
            const int kq = ks * 4 + (lane >> 4);
            bf16x8 af[4], bf[4];
#pragma unroll
            for (int mt = 0; mt < 4; ++mt) {
                int m = wm + mt * 16 + (lane & 15);
                af[mt] = *(const bf16x8*)&As[m * 64 + (kq ^ (m & 7)) * 8];
            }
#pragma unroll
            for (int nt = 0; nt < 4; ++nt) {
                int n = wn + nt * 16 + (lane & 15);
                bf[nt] = *(const bf16x8*)&Bs[n * 64 + (kq ^ (n & 7)) * 8];
            }
#pragma unroll
            for (int mt = 0; mt < 4; ++mt)
#pragma unroll
                for (int nt = 0; nt < 4; ++nt)
                    acc[mt][nt] = __builtin_amdgcn_mfma_f32_16x16x32_bf16(
                        af[mt], bf[nt], acc[mt][nt], 0, 0, 0);
        }
        __syncthreads();
    }

    const int cq = lane >> 4;
#pragma unroll
    for (int nt = 0; nt < 4; ++nt) {
        int col  = col0 + wn + nt * 16 + (lane & 15);
        float bv = bias[col];
#pragma unroll
        for (int mt = 0; mt < 4; ++mt) {
#pragma unroll
            for (int rI = 0; rI < 4; ++rI) {
                int rowg = row0 + wm + mt * 16 + cq * 4 + rI;
                out[(size_t)rowg * 256 + col] = acc[mt][nt][rI] + bv;
            }
        }
    }
}

// ---------------------------------------------------------------------------
// launcher
// ws: val     [0,          67108864)  B*8*HW*32 bf16
//     locattn [67108864,  100663296)  B*N*32 float4  (n-major)
//     mid     [100663296, 134217728)  B*N*256 bf16
//     Wt      [134217728, 134348800)  256*256 bf16
//     Wc_hi   [134348800, 134397952)  96*256 bf16
//     Wc_lo   [134397952, 134447104)  96*256 bf16
// ---------------------------------------------------------------------------
extern "C" void kernel_launch(void* const* d_in, const int* in_sizes, int n_in,
                              void* d_out, int out_size, void* d_ws, size_t ws_size,
                              hipStream_t stream) {
    const float* query  = (const float*)d_in[0];
    const float* refp   = (const float*)d_in[1];
    const float* value  = (const float*)d_in[2];
    const float* W_off  = (const float*)d_in[3];
    const float* b_off  = (const float*)d_in[4];
    const float* W_attn = (const float*)d_in[5];
    const float* b_attn = (const float*)d_in[6];
    const float* W_out  = (const float*)d_in[7];
    const float* b_out  = (const float*)d_in[8];
    float* out = (float*)d_out;

    char*           ws      = (char*)d_ws;
    __hip_bfloat16* val     = (__hip_bfloat16*)(ws);
    float4*         locattn = (float4*)(ws + 67108864);
    __hip_bfloat16* mid     = (__hip_bfloat16*)(ws + 100663296);
    __hip_bfloat16* Wt      = (__hip_bfloat16*)(ws + 134217728);
    short*          Wc_hi   = (short*)(ws + 134348800);
    short*          Wc_lo   = (short*)(ws + 134397952);

    kTP <<<dim3(4208), 256, 0, stream>>>(value, val, W_off, W_attn,
                                         Wc_hi, Wc_lo, W_out, Wt);
    kA1M<<<dim3((B_ * N_) / 128), 256, 0, stream>>>(query, refp, Wc_hi, Wc_lo,
                                                    b_off, b_attn, locattn);
    kA2 <<<dim3(B_ * HH * N_ / 64), 256, 0, stream>>>(locattn, val, mid);
    kC  <<<dim3((B_ * N_) / 128, C_ / 128), 256, 0, stream>>>(
        (const short*)mid, (const short*)Wt, b_out, out);
}